// Round 1
// baseline (189.882 us; speedup 1.0000x reference)
//
#include <hip/hip_runtime.h>
#include <math.h>

#define FEAT 4096
#define BATCH 4096

// Kernel 1: one block per row. Computes relu(2 - ||o1-o3|| + ||o1-o2||) per row.
__global__ __launch_bounds__(256) void row_dist_kernel(
    const float* __restrict__ o1, const float* __restrict__ o2,
    const float* __restrict__ o3, float* __restrict__ row_out)
{
    const int row = blockIdx.x;
    const int tid = threadIdx.x;
    const float4* p1 = (const float4*)(o1 + (size_t)row * FEAT);
    const float4* p2 = (const float4*)(o2 + (size_t)row * FEAT);
    const float4* p3 = (const float4*)(o3 + (size_t)row * FEAT);

    float s13 = 0.0f, s12 = 0.0f;
    // FEAT/4 = 1024 float4 per row; 256 threads -> 4 each, coalesced stride-256
    #pragma unroll
    for (int k = 0; k < 4; ++k) {
        const int idx = tid + k * 256;
        const float4 a = p1[idx];
        const float4 b = p2[idx];
        const float4 c = p3[idx];
        float d;
        d = a.x - c.x; s13 += d * d;
        d = a.y - c.y; s13 += d * d;
        d = a.z - c.z; s13 += d * d;
        d = a.w - c.w; s13 += d * d;
        d = a.x - b.x; s12 += d * d;
        d = a.y - b.y; s12 += d * d;
        d = a.z - b.z; s12 += d * d;
        d = a.w - b.w; s12 += d * d;
    }

    // wave(64)-level butterfly reduce
    #pragma unroll
    for (int off = 32; off > 0; off >>= 1) {
        s13 += __shfl_down(s13, off, 64);
        s12 += __shfl_down(s12, off, 64);
    }

    __shared__ float ls13[4];
    __shared__ float ls12[4];
    const int wave = tid >> 6;
    const int lane = tid & 63;
    if (lane == 0) { ls13[wave] = s13; ls12[wave] = s12; }
    __syncthreads();
    if (tid == 0) {
        const float t13 = ls13[0] + ls13[1] + ls13[2] + ls13[3];
        const float t12 = ls12[0] + ls12[1] + ls12[2] + ls12[3];
        const float compare = 2.0f - sqrtf(t13) + sqrtf(t12);
        row_out[row] = fmaxf(compare, 0.0f);
    }
}

// Kernel 2: reduce the BATCH row values, scale by BATCH (broadcast-sum semantics).
__global__ __launch_bounds__(1024) void final_reduce_kernel(
    const float* __restrict__ row_vals, float* __restrict__ out)
{
    const int tid = threadIdx.x;
    float s = 0.0f;
    #pragma unroll
    for (int k = 0; k < BATCH / 1024; ++k) s += row_vals[tid + k * 1024];

    #pragma unroll
    for (int off = 32; off > 0; off >>= 1) s += __shfl_down(s, off, 64);

    __shared__ float ls[16];
    const int wave = tid >> 6;
    const int lane = tid & 63;
    if (lane == 0) ls[wave] = s;
    __syncthreads();
    if (tid == 0) {
        float t = 0.0f;
        #pragma unroll
        for (int i = 0; i < 16; ++i) t += ls[i];
        out[0] = t * (float)BATCH;
    }
}

extern "C" void kernel_launch(void* const* d_in, const int* in_sizes, int n_in,
                              void* d_out, int out_size, void* d_ws, size_t ws_size,
                              hipStream_t stream) {
    const float* o1 = (const float*)d_in[0];
    const float* o2 = (const float*)d_in[1];
    const float* o3 = (const float*)d_in[2];
    float* row_ws = (float*)d_ws;          // BATCH floats of scratch
    float* out = (float*)d_out;            // single fp32 scalar

    row_dist_kernel<<<BATCH, 256, 0, stream>>>(o1, o2, o3, row_ws);
    final_reduce_kernel<<<1, 1024, 0, stream>>>(row_ws, out);
}